// Round 1
// baseline (1132.573 us; speedup 1.0000x reference)
//
#include <hip/hip_runtime.h>
#include <hip/hip_bf16.h>

#define B_  4
#define S_  2048
#define D_  1024
#define E_  8
#define K2_ 2048   // 2*D

#define CHUNKS 32
#define CLEN   64  // CHUNKS*CLEN == S_

// ---------------- math helpers (stable) ----------------
__device__ __forceinline__ float softplus_f(float x) {
    // log(1+e^x) = max(x,0) + log1p(exp(-|x|))
    return fmaxf(x, 0.0f) + log1pf(expf(-fabsf(x)));
}
__device__ __forceinline__ float logg_f(float x) {
    // x>=0: log(x+0.5) ; x<0: -softplus(-x) = x - log1p(exp(x))
    return (x >= 0.0f) ? logf(x + 0.5f) : (x - log1pf(expf(x)));
}
__device__ __forceinline__ float logaddexp_f(float a, float b) {
    float m = fmaxf(a, b);
    return m + log1pf(expf(fminf(a, b) - m));
}

// ---------------- 1. RMSNorm ----------------
// grid (S_, B_), block 256. Each block handles one (b,s) row of D=1024.
__global__ void rmsnorm_k(const float* __restrict__ in, const float* __restrict__ nw,
                          float* __restrict__ x) {
    int b = blockIdx.y, s = blockIdx.x, t = threadIdx.x;
    const float* row = in + ((size_t)b * S_ + s) * D_;
    float v[4]; float ss = 0.0f;
#pragma unroll
    for (int i = 0; i < 4; i++) { v[i] = row[t + 256 * i]; ss += v[i] * v[i]; }
#pragma unroll
    for (int o = 32; o > 0; o >>= 1) ss += __shfl_down(ss, o, 64);
    __shared__ float ls[4];
    if ((t & 63) == 0) ls[t >> 6] = ss;
    __syncthreads();
    float tot = ls[0] + ls[1] + ls[2] + ls[3];
    float rs = rsqrtf(tot * (1.0f / (float)D_) + 1e-6f);
    float* xr = x + ((size_t)b * S_ + s) * D_;
#pragma unroll
    for (int i = 0; i < 4; i++) xr[t + 256 * i] = v[i] * rs * nw[t + 256 * i];
}

// ---------------- 2a. column sums of x over S (for router mean) ----------------
// grid (D_/256, B_, 16), block 256. Each block sums 128 s-rows.
__global__ void xsum_k(const float* __restrict__ x, float* __restrict__ xs) {
    int d = blockIdx.x * 256 + threadIdx.x;
    int b = blockIdx.y;
    int s0 = blockIdx.z * 128;
    const float* p = x + ((size_t)b * S_ + s0) * D_ + d;
    float acc = 0.0f;
#pragma unroll 4
    for (int s = 0; s < 128; s++) { acc += *p; p += D_; }
    atomicAdd(&xs[b * D_ + d], acc);
}

// ---------------- 2b. router logits + softmax ----------------
// 1 block of 256. 32 (b,e) pairs, 8 threads each.
__global__ void router_k(const float* __restrict__ xs, const float* __restrict__ rw,
                         const float* __restrict__ rb, float* __restrict__ probs) {
    int t = threadIdx.x;
    int pair = t >> 3, sub = t & 7;     // pair 0..31
    int b = pair >> 3, e = pair & 7;
    float acc = 0.0f;
    for (int d = sub; d < D_; d += 8) acc += xs[b * D_ + d] * rw[e * D_ + d];
#pragma unroll
    for (int o = 4; o > 0; o >>= 1) acc += __shfl_down(acc, o, 8);
    __shared__ float lg[32];
    if (sub == 0) lg[pair] = acc * (1.0f / (float)S_) + rb[e];
    __syncthreads();
    if (t < 4) {
        float m = -1e30f;
        for (int e2 = 0; e2 < 8; e2++) m = fmaxf(m, lg[t * 8 + e2]);
        float ssum = 0.0f; float ex[8];
        for (int e2 = 0; e2 < 8; e2++) { ex[e2] = expf(lg[t * 8 + e2] - m); ssum += ex[e2]; }
        for (int e2 = 0; e2 < 8; e2++) probs[t * 8 + e2] = ex[e2] / ssum;
    }
}

// ---------------- 3. mix expert weights ----------------
// one thread per weight element; 8 expert reads -> 4 batch writes.
__global__ void mix_k(const float* __restrict__ probs, const float* __restrict__ whg_e,
                      const float* __restrict__ wout_e, float* __restrict__ Whg,
                      float* __restrict__ Wout) {
    __shared__ float P[32];
    int t = threadIdx.x;
    if (t < 32) P[t] = probs[t];
    __syncthreads();
    size_t i = (size_t)blockIdx.x * 256 + t;
    const size_t T1 = (size_t)K2_ * D_;  // 2097152
    const size_t T2 = (size_t)D_ * D_;   // 1048576
    if (i < T1) {
        float a0 = 0, a1 = 0, a2 = 0, a3 = 0;
#pragma unroll
        for (int e = 0; e < 8; e++) {
            float w = whg_e[(size_t)e * T1 + i];
            a0 += P[0 * 8 + e] * w; a1 += P[1 * 8 + e] * w;
            a2 += P[2 * 8 + e] * w; a3 += P[3 * 8 + e] * w;
        }
        Whg[0 * T1 + i] = a0; Whg[1 * T1 + i] = a1;
        Whg[2 * T1 + i] = a2; Whg[3 * T1 + i] = a3;
    } else {
        size_t j = i - T1;
        float a0 = 0, a1 = 0, a2 = 0, a3 = 0;
#pragma unroll
        for (int e = 0; e < 8; e++) {
            float w = wout_e[(size_t)e * T2 + j];
            a0 += P[0 * 8 + e] * w; a1 += P[1 * 8 + e] * w;
            a2 += P[2 * 8 + e] * w; a3 += P[3 * 8 + e] * w;
        }
        Wout[0 * T2 + j] = a0; Wout[1 * T2 + j] = a1;
        Wout[2 * T2 + j] = a2; Wout[3 * T2 + j] = a3;
    }
}

// ---------------- 4/6. f32 GEMM, C = A * B^T (+R), batched over grid.z ----------------
// A: M x K row-major, B: N x K row-major. 64x64 tile, BK=16, 4x4 per thread.
#define BM 64
#define BN 64
#define BKK 16
__global__ __launch_bounds__(256) void gemm_bt_f32(
    const float* __restrict__ A, const float* __restrict__ B,
    float* __restrict__ C, const float* __restrict__ R,
    int M, int N, int K, size_t sa, size_t sb, size_t sc, size_t sr) {
    int bz = blockIdx.z;
    A += (size_t)bz * sa; B += (size_t)bz * sb; C += (size_t)bz * sc;
    if (R) R += (size_t)bz * sr;
    int m0 = blockIdx.y * BM, n0 = blockIdx.x * BN;
    int t = threadIdx.x;
    int tx = t & 15, ty = t >> 4;
    __shared__ float As[BKK][BM + 4];
    __shared__ float Bs[BKK][BN + 4];
    float acc[4][4] = {};
    int lr = t >> 2;          // 0..63
    int lk = (t & 3) * 4;     // 0,4,8,12
    for (int k0 = 0; k0 < K; k0 += BKK) {
        float4 av = *(const float4*)(A + (size_t)(m0 + lr) * K + k0 + lk);
        float4 bv = *(const float4*)(B + (size_t)(n0 + lr) * K + k0 + lk);
        As[lk + 0][lr] = av.x; As[lk + 1][lr] = av.y; As[lk + 2][lr] = av.z; As[lk + 3][lr] = av.w;
        Bs[lk + 0][lr] = bv.x; Bs[lk + 1][lr] = bv.y; Bs[lk + 2][lr] = bv.z; Bs[lk + 3][lr] = bv.w;
        __syncthreads();
#pragma unroll
        for (int k = 0; k < BKK; k++) {
            float4 a = *(const float4*)(&As[k][ty * 4]);
            float4 bq = *(const float4*)(&Bs[k][tx * 4]);
            float aa[4] = {a.x, a.y, a.z, a.w};
            float bb[4] = {bq.x, bq.y, bq.z, bq.w};
#pragma unroll
            for (int i = 0; i < 4; i++)
#pragma unroll
                for (int j = 0; j < 4; j++) acc[i][j] += aa[i] * bb[j];
        }
        __syncthreads();
    }
#pragma unroll
    for (int i = 0; i < 4; i++) {
        int m = m0 + ty * 4 + i;
#pragma unroll
        for (int j = 0; j < 4; j++) {
            int n = n0 + tx * 4 + j;
            float vv = acc[i][j];
            if (R) vv += R[(size_t)m * N + n];
            C[(size_t)m * N + n] = vv;
        }
    }
}

// ---------------- 5. chunked log-space scan ----------------
// phase A: per-chunk composed (A = sum lc, V = chunk-local scan from -inf)
__global__ void scanA_k(const float* __restrict__ hg, float* __restrict__ Ac,
                        float* __restrict__ Vc) {
    int b = blockIdx.z, c = blockIdx.y;
    int d = blockIdx.x * 256 + threadIdx.x;
    const float* p = hg + ((size_t)b * S_ + c * CLEN) * K2_ + d;
    float Aa = 0.0f, V = -1e30f;
    for (int s = 0; s < CLEN; s++) {
        float hid = p[0], g = p[D_];
        float lc = -softplus_f(g);
        float lv = -softplus_f(-g) + logg_f(hid);
        Aa += lc;
        V = logaddexp_f(V + lc, lv);
        p += K2_;
    }
    size_t idx = ((size_t)(b * CHUNKS + c)) * D_ + d;
    Ac[idx] = Aa; Vc[idx] = V;
}

// phase B: scan over chunk states; record each chunk's initial L
__global__ void scanB_k(const float* __restrict__ Ac, const float* __restrict__ Vc,
                        float* __restrict__ Li) {
    int b = blockIdx.y;
    int d = blockIdx.x * 256 + threadIdx.x;
    float L = -1e30f;
    for (int c = 0; c < CHUNKS; c++) {
        size_t idx = ((size_t)(b * CHUNKS + c)) * D_ + d;
        Li[idx] = L;
        L = logaddexp_f(Ac[idx] + L, Vc[idx]);
    }
}

// phase C: replay chunk with true initial L, emit h = exp(L); also new_state
__global__ void scanC_k(const float* __restrict__ hg, const float* __restrict__ Li,
                        float* __restrict__ h, float* __restrict__ ns) {
    int b = blockIdx.z, c = blockIdx.y;
    int d = blockIdx.x * 256 + threadIdx.x;
    const float* p = hg + ((size_t)b * S_ + c * CLEN) * K2_ + d;
    float L = Li[((size_t)(b * CHUNKS + c)) * D_ + d];
    for (int s = 0; s < CLEN; s++) {
        float hid = p[0], g = p[D_];
        float lc = -softplus_f(g);
        float lv = -softplus_f(-g) + logg_f(hid);
        L = logaddexp_f(L + lc, lv);
        float hv = expf(L);
        h[((size_t)b * S_ + c * CLEN + s) * D_ + d] = hv;
        if (c * CLEN + s == S_ - 1) ns[b * D_ + d] = hv;
        p += K2_;
    }
}

__global__ void aux_k(float* o) { if (threadIdx.x == 0) o[0] = 0.0f; }

// ---------------- launcher ----------------
extern "C" void kernel_launch(void* const* d_in, const int* in_sizes, int n_in,
                              void* d_out_v, int out_size, void* d_ws, size_t ws_size,
                              hipStream_t stream) {
    const float* inputs = (const float*)d_in[0];
    const float* nw     = (const float*)d_in[1];
    const float* rw     = (const float*)d_in[2];
    const float* rb     = (const float*)d_in[3];
    const float* whg_e  = (const float*)d_in[4];
    const float* wout_e = (const float*)d_in[5];
    float* out = (float*)d_out_v;

    float* ws = (float*)d_ws;
    // float-offset layout (total ~145.5 MB)
    float* x     = ws;                 // 8388608  (reused as h after GEMM1)
    float* hg    = ws + 8388608;       // 16777216
    float* Whg   = ws + 25165824;      // 8388608
    float* Wout  = ws + 33554432;      // 4194304
    float* xsum  = ws + 37748736;      // 4096
    float* probs = ws + 37752832;      // 32
    float* Ac    = ws + 37752864;      // 131072
    float* Vc    = ws + 37883936;      // 131072
    float* Li    = ws + 38015008;      // 131072

    hipMemsetAsync(xsum, 0, (size_t)B_ * D_ * sizeof(float), stream);

    rmsnorm_k<<<dim3(S_, B_), 256, 0, stream>>>(inputs, nw, x);
    xsum_k<<<dim3(D_ / 256, B_, 16), 256, 0, stream>>>(x, xsum);
    router_k<<<1, 256, 0, stream>>>(xsum, rw, rb, probs);
    mix_k<<<12288, 256, 0, stream>>>(probs, whg_e, wout_e, Whg, Wout);

    // hg[b] (2048x2048) = x[b] (2048x1024) * Whg[b]^T (2048x1024)
    gemm_bt_f32<<<dim3(K2_ / BN, S_ / BM, B_), 256, 0, stream>>>(
        x, Whg, hg, nullptr, S_, K2_, D_,
        (size_t)S_ * D_, (size_t)K2_ * D_, (size_t)S_ * K2_, 0);

    scanA_k<<<dim3(D_ / 256, CHUNKS, B_), 256, 0, stream>>>(hg, Ac, Vc);
    scanB_k<<<dim3(D_ / 256, B_), 256, 0, stream>>>(Ac, Vc, Li);
    scanC_k<<<dim3(D_ / 256, CHUNKS, B_), 256, 0, stream>>>(hg, Li, x, out + (size_t)B_ * S_ * D_);

    // out[b] (2048x1024) = h[b] (2048x1024) * Wout[b]^T (1024x1024) + inputs[b]
    gemm_bt_f32<<<dim3(D_ / BN, S_ / BM, B_), 256, 0, stream>>>(
        x, Wout, out, inputs, S_, D_, D_,
        (size_t)S_ * D_, (size_t)D_ * D_, (size_t)S_ * D_, (size_t)S_ * D_);

    aux_k<<<1, 64, 0, stream>>>(out + (size_t)B_ * S_ * D_ + (size_t)B_ * D_);
}

// Round 2
// 539.551 us; speedup vs baseline: 2.0991x; 2.0991x over previous
//
#include <hip/hip_runtime.h>
#include <hip/hip_bf16.h>

#define B_  4
#define S_  2048
#define D_  1024
#define E_  8
#define K2_ 2048   // 2*D

#define CHUNKS 32
#define CLEN   64  // CHUNKS*CLEN == S_

typedef __attribute__((ext_vector_type(8))) short short8;   // 8 bf16 (4 VGPRs)
typedef __attribute__((ext_vector_type(4))) float floatx4;  // 4 fp32 acc

// ---------------- math helpers (stable) ----------------
__device__ __forceinline__ float softplus_f(float x) {
    return fmaxf(x, 0.0f) + log1pf(expf(-fabsf(x)));
}
__device__ __forceinline__ float logg_f(float x) {
    return (x >= 0.0f) ? logf(x + 0.5f) : (x - log1pf(expf(x)));
}
__device__ __forceinline__ float logaddexp_f(float a, float b) {
    float m = fmaxf(a, b);
    return m + log1pf(expf(fminf(a, b) - m));
}

__device__ __forceinline__ void gld16(const void* g, const void* l) {
    __builtin_amdgcn_global_load_lds(
        (const __attribute__((address_space(1))) unsigned int*)g,
        (__attribute__((address_space(3))) unsigned int*)l, 16, 0, 0);
}

// ---------------- 1. RMSNorm (f32 in -> bf16 out) ----------------
__global__ void rmsnorm_k(const float* __restrict__ in, const float* __restrict__ nw,
                          __hip_bfloat16* __restrict__ x) {
    int b = blockIdx.y, s = blockIdx.x, t = threadIdx.x;
    const float* row = in + ((size_t)b * S_ + s) * D_;
    float v[4]; float ss = 0.0f;
#pragma unroll
    for (int i = 0; i < 4; i++) { v[i] = row[t + 256 * i]; ss += v[i] * v[i]; }
#pragma unroll
    for (int o = 32; o > 0; o >>= 1) ss += __shfl_down(ss, o, 64);
    __shared__ float ls[4];
    if ((t & 63) == 0) ls[t >> 6] = ss;
    __syncthreads();
    float tot = ls[0] + ls[1] + ls[2] + ls[3];
    float rs = rsqrtf(tot * (1.0f / (float)D_) + 1e-6f);
    __hip_bfloat16* xr = x + ((size_t)b * S_ + s) * D_;
#pragma unroll
    for (int i = 0; i < 4; i++)
        xr[t + 256 * i] = __float2bfloat16(v[i] * rs * nw[t + 256 * i]);
}

// ---------------- 2a. column sums of x over S (router mean) ----------------
__global__ void xsum_k(const __hip_bfloat16* __restrict__ x, float* __restrict__ xs) {
    int d = blockIdx.x * 256 + threadIdx.x;
    int b = blockIdx.y;
    int s0 = blockIdx.z * 128;
    const __hip_bfloat16* p = x + ((size_t)b * S_ + s0) * D_ + d;
    float acc = 0.0f;
#pragma unroll 4
    for (int s = 0; s < 128; s++) { acc += __bfloat162float(*p); p += D_; }
    atomicAdd(&xs[b * D_ + d], acc);
}

// ---------------- 2b. router logits + softmax ----------------
__global__ void router_k(const float* __restrict__ xs, const float* __restrict__ rw,
                         const float* __restrict__ rb, float* __restrict__ probs) {
    int t = threadIdx.x;
    int pair = t >> 3, sub = t & 7;
    int b = pair >> 3, e = pair & 7;
    float acc = 0.0f;
    for (int d = sub; d < D_; d += 8) acc += xs[b * D_ + d] * rw[e * D_ + d];
#pragma unroll
    for (int o = 4; o > 0; o >>= 1) acc += __shfl_down(acc, o, 8);
    __shared__ float lg[32];
    if (sub == 0) lg[pair] = acc * (1.0f / (float)S_) + rb[e];
    __syncthreads();
    if (t < 4) {
        float m = -1e30f;
        for (int e2 = 0; e2 < 8; e2++) m = fmaxf(m, lg[t * 8 + e2]);
        float ssum = 0.0f; float ex[8];
        for (int e2 = 0; e2 < 8; e2++) { ex[e2] = expf(lg[t * 8 + e2] - m); ssum += ex[e2]; }
        for (int e2 = 0; e2 < 8; e2++) probs[t * 8 + e2] = ex[e2] / ssum;
    }
}

// ---------------- 3. mix expert weights (f32 experts -> bf16 mixed) ----------------
__global__ void mix_k(const float* __restrict__ probs, const float* __restrict__ whg_e,
                      const float* __restrict__ wout_e, __hip_bfloat16* __restrict__ Whg,
                      __hip_bfloat16* __restrict__ Wout) {
    __shared__ float P[32];
    int t = threadIdx.x;
    if (t < 32) P[t] = probs[t];
    __syncthreads();
    size_t i = (size_t)blockIdx.x * 256 + t;
    const size_t T1 = (size_t)K2_ * D_;
    const size_t T2 = (size_t)D_ * D_;
    if (i < T1) {
        float a0 = 0, a1 = 0, a2 = 0, a3 = 0;
#pragma unroll
        for (int e = 0; e < 8; e++) {
            float w = whg_e[(size_t)e * T1 + i];
            a0 += P[0 * 8 + e] * w; a1 += P[1 * 8 + e] * w;
            a2 += P[2 * 8 + e] * w; a3 += P[3 * 8 + e] * w;
        }
        Whg[0 * T1 + i] = __float2bfloat16(a0); Whg[1 * T1 + i] = __float2bfloat16(a1);
        Whg[2 * T1 + i] = __float2bfloat16(a2); Whg[3 * T1 + i] = __float2bfloat16(a3);
    } else {
        size_t j = i - T1;
        float a0 = 0, a1 = 0, a2 = 0, a3 = 0;
#pragma unroll
        for (int e = 0; e < 8; e++) {
            float w = wout_e[(size_t)e * T2 + j];
            a0 += P[0 * 8 + e] * w; a1 += P[1 * 8 + e] * w;
            a2 += P[2 * 8 + e] * w; a3 += P[3 * 8 + e] * w;
        }
        Wout[0 * T2 + j] = __float2bfloat16(a0); Wout[1 * T2 + j] = __float2bfloat16(a1);
        Wout[2 * T2 + j] = __float2bfloat16(a2); Wout[3 * T2 + j] = __float2bfloat16(a3);
    }
}

// ---------------- 4/6. bf16 MFMA GEMM, C = A * B^T (+R), batched over grid.z ----
// A: M x K row-major bf16, B: N x K row-major bf16, C f32. m97 structure:
// 128x128 tile, BK=64, global_load_lds w=16 staging, ds_read_b128 frags.
#define TM 128
#define TN 128
#define TBK 64
__global__ __launch_bounds__(256) void gemm_bf16_bt(
    const __hip_bfloat16* __restrict__ A, const __hip_bfloat16* __restrict__ Bm,
    float* __restrict__ C, const float* __restrict__ R,
    int M, int N, int K, size_t sa, size_t sb, size_t sc, size_t sr) {
    int bz = blockIdx.z;
    A += (size_t)bz * sa; Bm += (size_t)bz * sb; C += (size_t)bz * sc;
    if (R) R += (size_t)bz * sr;
    int m0 = blockIdx.y * TM, n0 = blockIdx.x * TN;
    __shared__ __hip_bfloat16 lA[TM][TBK];   // unpadded: global_load_lds layout
    __shared__ __hip_bfloat16 lB[TN][TBK];
    int t = threadIdx.x;
    int w = t >> 6, lane = t & 63;
    int lm = lane & 15, quad = lane >> 4;
    int wr = w >> 1, wc = w & 1;             // 2x2 waves, 64x64 each
    floatx4 acc[4][4] = {};
    int srow = lane >> 3;                    // 0..7 within 8-row slab
    int scolb = (lane & 7) * 16;             // byte offset within 128B row

    for (int k0 = 0; k0 < K; k0 += TBK) {
#pragma unroll
        for (int it = 0; it < 4; it++) {
            int r0 = (w * 4 + it) * 8;       // slab base row (wave-uniform)
            gld16((const char*)(A + (size_t)(m0 + r0 + srow) * K + k0) + scolb,
                  &lA[r0][0]);
            gld16((const char*)(Bm + (size_t)(n0 + r0 + srow) * K + k0) + scolb,
                  &lB[r0][0]);
        }
        __syncthreads();
#pragma unroll
        for (int kk = 0; kk < TBK; kk += 32) {
            short8 af[4], bf[4];
#pragma unroll
            for (int i = 0; i < 4; i++)
                af[i] = *(const short8*)(&lA[wr * 64 + i * 16 + lm][kk + quad * 8]);
#pragma unroll
            for (int j = 0; j < 4; j++)
                bf[j] = *(const short8*)(&lB[wc * 64 + j * 16 + lm][kk + quad * 8]);
#pragma unroll
            for (int i = 0; i < 4; i++)
#pragma unroll
                for (int j = 0; j < 4; j++)
                    acc[i][j] = __builtin_amdgcn_mfma_f32_16x16x32_bf16(
                        af[i], bf[j], acc[i][j], 0, 0, 0);
        }
        __syncthreads();
    }
#pragma unroll
    for (int i = 0; i < 4; i++) {
#pragma unroll
        for (int j = 0; j < 4; j++) {
#pragma unroll
            for (int r = 0; r < 4; r++) {
                int m = m0 + wr * 64 + i * 16 + quad * 4 + r;
                int n = n0 + wc * 64 + j * 16 + lm;
                float v = acc[i][j][r];
                if (R) v += R[(size_t)m * N + n];
                C[(size_t)m * N + n] = v;
            }
        }
    }
}

// ---------------- 5. chunked log-space scan ----------------
__global__ void scanA_k(const float* __restrict__ hg, float* __restrict__ Ac,
                        float* __restrict__ Vc) {
    int b = blockIdx.z, c = blockIdx.y;
    int d = blockIdx.x * 256 + threadIdx.x;
    const float* p = hg + ((size_t)b * S_ + c * CLEN) * K2_ + d;
    float Aa = 0.0f, V = -1e30f;
    for (int s = 0; s < CLEN; s++) {
        float hid = p[0], g = p[D_];
        float lc = -softplus_f(g);
        float lv = -softplus_f(-g) + logg_f(hid);
        Aa += lc;
        V = logaddexp_f(V + lc, lv);
        p += K2_;
    }
    size_t idx = ((size_t)(b * CHUNKS + c)) * D_ + d;
    Ac[idx] = Aa; Vc[idx] = V;
}

__global__ void scanB_k(const float* __restrict__ Ac, const float* __restrict__ Vc,
                        float* __restrict__ Li) {
    int b = blockIdx.y;
    int d = blockIdx.x * 256 + threadIdx.x;
    float L = -1e30f;
    for (int c = 0; c < CHUNKS; c++) {
        size_t idx = ((size_t)(b * CHUNKS + c)) * D_ + d;
        Li[idx] = L;
        L = logaddexp_f(Ac[idx] + L, Vc[idx]);
    }
}

// phase C: replay with true initial L; h out in bf16 (GEMM2 A operand), ns f32
__global__ void scanC_k(const float* __restrict__ hg, const float* __restrict__ Li,
                        __hip_bfloat16* __restrict__ h, float* __restrict__ ns) {
    int b = blockIdx.z, c = blockIdx.y;
    int d = blockIdx.x * 256 + threadIdx.x;
    const float* p = hg + ((size_t)b * S_ + c * CLEN) * K2_ + d;
    float L = Li[((size_t)(b * CHUNKS + c)) * D_ + d];
    for (int s = 0; s < CLEN; s++) {
        float hid = p[0], g = p[D_];
        float lc = -softplus_f(g);
        float lv = -softplus_f(-g) + logg_f(hid);
        L = logaddexp_f(L + lc, lv);
        float hv = expf(L);
        h[((size_t)b * S_ + c * CLEN + s) * D_ + d] = __float2bfloat16(hv);
        if (c * CLEN + s == S_ - 1) ns[b * D_ + d] = hv;
        p += K2_;
    }
}

__global__ void aux_k(float* o) { if (threadIdx.x == 0) o[0] = 0.0f; }

// ---------------- launcher ----------------
extern "C" void kernel_launch(void* const* d_in, const int* in_sizes, int n_in,
                              void* d_out_v, int out_size, void* d_ws, size_t ws_size,
                              hipStream_t stream) {
    const float* inputs = (const float*)d_in[0];
    const float* nw     = (const float*)d_in[1];
    const float* rw     = (const float*)d_in[2];
    const float* rb     = (const float*)d_in[3];
    const float* whg_e  = (const float*)d_in[4];
    const float* wout_e = (const float*)d_in[5];
    float* out = (float*)d_out_v;

    float* ws = (float*)d_ws;
    // float-unit offsets (all 16B aligned)
    float*          hg      = ws;                          // 16777216 f32 (64 MB)
    __hip_bfloat16* x_bf    = (__hip_bfloat16*)(ws + 16777216); // 8388608 bf16
    __hip_bfloat16* h_bf    = (__hip_bfloat16*)(ws + 20971520); // 8388608 bf16
    __hip_bfloat16* Whg_bf  = (__hip_bfloat16*)(ws + 25165824); // 8388608 bf16
    __hip_bfloat16* Wout_bf = (__hip_bfloat16*)(ws + 29360128); // 4194304 bf16
    float* xsum  = ws + 31457280;  // 4096
    float* probs = ws + 31461376;  // 32
    float* Ac    = ws + 31461408;  // 131072
    float* Vc    = ws + 31592480;  // 131072
    float* Li    = ws + 31723552;  // 131072

    hipMemsetAsync(xsum, 0, (size_t)B_ * D_ * sizeof(float), stream);

    rmsnorm_k<<<dim3(S_, B_), 256, 0, stream>>>(inputs, nw, x_bf);
    xsum_k<<<dim3(D_ / 256, B_, 16), 256, 0, stream>>>(x_bf, xsum);
    router_k<<<1, 256, 0, stream>>>(xsum, rw, rb, probs);
    mix_k<<<12288, 256, 0, stream>>>(probs, whg_e, wout_e, Whg_bf, Wout_bf);

    // hg[b] (2048x2048) = x[b] (2048x1024) * Whg[b]^T
    gemm_bf16_bt<<<dim3(K2_ / TN, S_ / TM, B_), 256, 0, stream>>>(
        x_bf, Whg_bf, hg, nullptr, S_, K2_, D_,
        (size_t)S_ * D_, (size_t)K2_ * D_, (size_t)S_ * K2_, 0);

    scanA_k<<<dim3(D_ / 256, CHUNKS, B_), 256, 0, stream>>>(hg, Ac, Vc);
    scanB_k<<<dim3(D_ / 256, B_), 256, 0, stream>>>(Ac, Vc, Li);
    scanC_k<<<dim3(D_ / 256, CHUNKS, B_), 256, 0, stream>>>(
        hg, Li, h_bf, out + (size_t)B_ * S_ * D_);

    // out[b] (2048x1024) = h[b] (2048x1024) * Wout[b]^T + inputs[b]
    gemm_bf16_bt<<<dim3(D_ / TN, S_ / TM, B_), 256, 0, stream>>>(
        h_bf, Wout_bf, out, inputs, S_, D_, D_,
        (size_t)S_ * D_, (size_t)D_ * D_, (size_t)S_ * D_, (size_t)S_ * D_);

    aux_k<<<1, 64, 0, stream>>>(out + (size_t)B_ * S_ * D_ + (size_t)B_ * D_);
}

// Round 3
// 358.519 us; speedup vs baseline: 3.1590x; 1.5049x over previous
//
#include <hip/hip_runtime.h>
#include <hip/hip_bf16.h>

#define B_  4
#define S_  2048
#define D_  1024
#define E_  8
#define K2_ 2048   // 2*D

#define CHUNKS 32
#define CLEN   64  // CHUNKS*CLEN == S_

typedef __attribute__((ext_vector_type(8))) short short8;   // 8 bf16 (4 VGPRs)
typedef __attribute__((ext_vector_type(4))) float floatx4;  // 4 fp32 acc

__device__ __forceinline__ void gld16(const void* g, const void* l) {
    __builtin_amdgcn_global_load_lds(
        (const __attribute__((address_space(1))) unsigned int*)g,
        (__attribute__((address_space(3))) unsigned int*)l, 16, 0, 0);
}

// ---------------- 1. RMSNorm (f32 in -> bf16 out) ----------------
__global__ void rmsnorm_k(const float* __restrict__ in, const float* __restrict__ nw,
                          __hip_bfloat16* __restrict__ x) {
    int b = blockIdx.y, s = blockIdx.x, t = threadIdx.x;
    const float* row = in + ((size_t)b * S_ + s) * D_;
    float v[4]; float ss = 0.0f;
#pragma unroll
    for (int i = 0; i < 4; i++) { v[i] = row[t + 256 * i]; ss += v[i] * v[i]; }
#pragma unroll
    for (int o = 32; o > 0; o >>= 1) ss += __shfl_down(ss, o, 64);
    __shared__ float ls[4];
    if ((t & 63) == 0) ls[t >> 6] = ss;
    __syncthreads();
    float tot = ls[0] + ls[1] + ls[2] + ls[3];
    float rs = rsqrtf(tot * (1.0f / (float)D_) + 1e-6f);
    __hip_bfloat16* xr = x + ((size_t)b * S_ + s) * D_;
#pragma unroll
    for (int i = 0; i < 4; i++)
        xr[t + 256 * i] = __float2bfloat16(v[i] * rs * nw[t + 256 * i]);
}

// ---------------- 2a. column sums of x over S (router mean) ----------------
__global__ void xsum_k(const __hip_bfloat16* __restrict__ x, float* __restrict__ xs) {
    int d = blockIdx.x * 256 + threadIdx.x;
    int b = blockIdx.y;
    int s0 = blockIdx.z * 128;
    const __hip_bfloat16* p = x + ((size_t)b * S_ + s0) * D_ + d;
    float acc = 0.0f;
#pragma unroll 4
    for (int s = 0; s < 128; s++) { acc += __bfloat162float(*p); p += D_; }
    atomicAdd(&xs[b * D_ + d], acc);
}

// ---------------- 2b. router logits + softmax ----------------
__global__ void router_k(const float* __restrict__ xs, const float* __restrict__ rw,
                         const float* __restrict__ rb, float* __restrict__ probs) {
    int t = threadIdx.x;
    int pair = t >> 3, sub = t & 7;
    int b = pair >> 3, e = pair & 7;
    float acc = 0.0f;
    for (int d = sub; d < D_; d += 8) acc += xs[b * D_ + d] * rw[e * D_ + d];
#pragma unroll
    for (int o = 4; o > 0; o >>= 1) acc += __shfl_down(acc, o, 8);
    __shared__ float lg[32];
    if (sub == 0) lg[pair] = acc * (1.0f / (float)S_) + rb[e];
    __syncthreads();
    if (t < 4) {
        float m = -1e30f;
        for (int e2 = 0; e2 < 8; e2++) m = fmaxf(m, lg[t * 8 + e2]);
        float ssum = 0.0f; float ex[8];
        for (int e2 = 0; e2 < 8; e2++) { ex[e2] = expf(lg[t * 8 + e2] - m); ssum += ex[e2]; }
        for (int e2 = 0; e2 < 8; e2++) probs[t * 8 + e2] = ex[e2] / ssum;
    }
}

// ---------------- 3. mix expert weights (f32 experts -> bf16 mixed) ----------------
__global__ void mix_k(const float* __restrict__ probs, const float* __restrict__ whg_e,
                      const float* __restrict__ wout_e, __hip_bfloat16* __restrict__ Whg,
                      __hip_bfloat16* __restrict__ Wout) {
    __shared__ float P[32];
    int t = threadIdx.x;
    if (t < 32) P[t] = probs[t];
    __syncthreads();
    size_t i = (size_t)blockIdx.x * 256 + t;
    const size_t T1 = (size_t)K2_ * D_;
    const size_t T2 = (size_t)D_ * D_;
    if (i < T1) {
        float a0 = 0, a1 = 0, a2 = 0, a3 = 0;
#pragma unroll
        for (int e = 0; e < 8; e++) {
            float w = whg_e[(size_t)e * T1 + i];
            a0 += P[0 * 8 + e] * w; a1 += P[1 * 8 + e] * w;
            a2 += P[2 * 8 + e] * w; a3 += P[3 * 8 + e] * w;
        }
        Whg[0 * T1 + i] = __float2bfloat16(a0); Whg[1 * T1 + i] = __float2bfloat16(a1);
        Whg[2 * T1 + i] = __float2bfloat16(a2); Whg[3 * T1 + i] = __float2bfloat16(a3);
    } else {
        size_t j = i - T1;
        float a0 = 0, a1 = 0, a2 = 0, a3 = 0;
#pragma unroll
        for (int e = 0; e < 8; e++) {
            float w = wout_e[(size_t)e * T2 + j];
            a0 += P[0 * 8 + e] * w; a1 += P[1 * 8 + e] * w;
            a2 += P[2 * 8 + e] * w; a3 += P[3 * 8 + e] * w;
        }
        Wout[0 * T2 + j] = __float2bfloat16(a0); Wout[1 * T2 + j] = __float2bfloat16(a1);
        Wout[2 * T2 + j] = __float2bfloat16(a2); Wout[3 * T2 + j] = __float2bfloat16(a3);
    }
}

// ---------------- 4. fused GEMM1 + (c,v) epilogue ----------------
// Per block: rows m0..m0+127 of x (M=2048,K=1024), hidden cols n0..n0+63 AND
// gate cols (n0+1024)..(n0+1087) of Whg^T, accumulated concurrently.
// Epilogue: c = sigmoid(-gate), v = sigmoid(gate)*g_fn(hid), store float2.
__global__ __launch_bounds__(256) void gemm_hg_cv(
    const __hip_bfloat16* __restrict__ A, const __hip_bfloat16* __restrict__ Bm,
    float* __restrict__ cv) {
    const int K = D_;
    int bz = blockIdx.z;
    A  += (size_t)bz * S_ * D_;
    Bm += (size_t)bz * K2_ * D_;
    float2* CV = (float2*)cv + (size_t)bz * S_ * D_;
    int m0 = blockIdx.y * 128, n0 = blockIdx.x * 64;
    __shared__ __hip_bfloat16 lA[128][64];
    __shared__ __hip_bfloat16 lBh[64][64];
    __shared__ __hip_bfloat16 lBg[64][64];
    int t = threadIdx.x;
    int w = t >> 6, lane = t & 63;
    int lm = lane & 15, quad = lane >> 4;
    int wr = w >> 1, wc = w & 1;             // wave tile: 64 rows x 32 cols
    floatx4 acch[4][2] = {};
    floatx4 accg[4][2] = {};
    int srow = lane >> 3;                    // 0..7
    int scolb = (lane & 7) * 16;             // byte col offset
    const __hip_bfloat16* Bh = Bm;                    // hidden rows 0..1023
    const __hip_bfloat16* Bg = Bm + (size_t)D_ * K;   // gate rows 1024..2047

    for (int k0 = 0; k0 < K; k0 += 64) {
#pragma unroll
        for (int it = 0; it < 4; it++) {
            int r0 = (w * 4 + it) * 8;
            gld16((const char*)(A + (size_t)(m0 + r0 + srow) * K + k0) + scolb,
                  &lA[r0][0]);
        }
#pragma unroll
        for (int it = 0; it < 2; it++) {
            int r0 = (w * 2 + it) * 8;
            gld16((const char*)(Bh + (size_t)(n0 + r0 + srow) * K + k0) + scolb,
                  &lBh[r0][0]);
            gld16((const char*)(Bg + (size_t)(n0 + r0 + srow) * K + k0) + scolb,
                  &lBg[r0][0]);
        }
        __syncthreads();
#pragma unroll
        for (int kk = 0; kk < 64; kk += 32) {
            short8 af[4], bh[2], bg[2];
#pragma unroll
            for (int i = 0; i < 4; i++)
                af[i] = *(const short8*)(&lA[wr * 64 + i * 16 + lm][kk + quad * 8]);
#pragma unroll
            for (int j = 0; j < 2; j++) {
                bh[j] = *(const short8*)(&lBh[wc * 32 + j * 16 + lm][kk + quad * 8]);
                bg[j] = *(const short8*)(&lBg[wc * 32 + j * 16 + lm][kk + quad * 8]);
            }
#pragma unroll
            for (int i = 0; i < 4; i++)
#pragma unroll
                for (int j = 0; j < 2; j++) {
                    acch[i][j] = __builtin_amdgcn_mfma_f32_16x16x32_bf16(
                        af[i], bh[j], acch[i][j], 0, 0, 0);
                    accg[i][j] = __builtin_amdgcn_mfma_f32_16x16x32_bf16(
                        af[i], bg[j], accg[i][j], 0, 0, 0);
                }
        }
        __syncthreads();
    }
#pragma unroll
    for (int i = 0; i < 4; i++) {
#pragma unroll
        for (int j = 0; j < 2; j++) {
#pragma unroll
            for (int r = 0; r < 4; r++) {
                int m = m0 + wr * 64 + i * 16 + quad * 4 + r;
                int n = n0 + wc * 32 + j * 16 + lm;
                float hid = acch[i][j][r];
                float g   = accg[i][j][r];
                float c  = 1.0f / (1.0f + expf(g));    // sigmoid(-g), inf-safe
                float sg = 1.0f / (1.0f + expf(-g));   // sigmoid(g),  inf-safe
                float gfn = (hid >= 0.0f) ? (hid + 0.5f)
                                          : (1.0f / (1.0f + expf(-hid)));
                CV[(size_t)m * D_ + n] = make_float2(c, sg * gfn);
            }
        }
    }
}

// ---------------- 5/6. bf16 MFMA GEMM, C = A * B^T (+R) --------------------
#define TM 128
#define TN 128
#define TBK 64
__global__ __launch_bounds__(256) void gemm_bf16_bt(
    const __hip_bfloat16* __restrict__ A, const __hip_bfloat16* __restrict__ Bm,
    float* __restrict__ C, const float* __restrict__ R,
    int M, int N, int K, size_t sa, size_t sb, size_t sc, size_t sr) {
    int bz = blockIdx.z;
    A += (size_t)bz * sa; Bm += (size_t)bz * sb; C += (size_t)bz * sc;
    if (R) R += (size_t)bz * sr;
    int m0 = blockIdx.y * TM, n0 = blockIdx.x * TN;
    __shared__ __hip_bfloat16 lA[TM][TBK];
    __shared__ __hip_bfloat16 lB[TN][TBK];
    int t = threadIdx.x;
    int w = t >> 6, lane = t & 63;
    int lm = lane & 15, quad = lane >> 4;
    int wr = w >> 1, wc = w & 1;
    floatx4 acc[4][4] = {};
    int srow = lane >> 3;
    int scolb = (lane & 7) * 16;

    for (int k0 = 0; k0 < K; k0 += TBK) {
#pragma unroll
        for (int it = 0; it < 4; it++) {
            int r0 = (w * 4 + it) * 8;
            gld16((const char*)(A + (size_t)(m0 + r0 + srow) * K + k0) + scolb,
                  &lA[r0][0]);
            gld16((const char*)(Bm + (size_t)(n0 + r0 + srow) * K + k0) + scolb,
                  &lB[r0][0]);
        }
        __syncthreads();
#pragma unroll
        for (int kk = 0; kk < TBK; kk += 32) {
            short8 af[4], bf[4];
#pragma unroll
            for (int i = 0; i < 4; i++)
                af[i] = *(const short8*)(&lA[wr * 64 + i * 16 + lm][kk + quad * 8]);
#pragma unroll
            for (int j = 0; j < 4; j++)
                bf[j] = *(const short8*)(&lB[wc * 64 + j * 16 + lm][kk + quad * 8]);
#pragma unroll
            for (int i = 0; i < 4; i++)
#pragma unroll
                for (int j = 0; j < 4; j++)
                    acc[i][j] = __builtin_amdgcn_mfma_f32_16x16x32_bf16(
                        af[i], bf[j], acc[i][j], 0, 0, 0);
        }
        __syncthreads();
    }
#pragma unroll
    for (int i = 0; i < 4; i++) {
#pragma unroll
        for (int j = 0; j < 4; j++) {
#pragma unroll
            for (int r = 0; r < 4; r++) {
                int m = m0 + wr * 64 + i * 16 + quad * 4 + r;
                int n = n0 + wc * 64 + j * 16 + lm;
                float v = acc[i][j][r];
                if (R) v += R[(size_t)m * N + n];
                C[(size_t)m * N + n] = v;
            }
        }
    }
}

// ---------------- 5. chunked LINEAR scan over cv ----------------
// phase A: per-chunk composition (Cc = prod c, Vc = chunk scan from 0)
__global__ void scanA_k(const float* __restrict__ cv, float* __restrict__ Cc,
                        float* __restrict__ Vc) {
    int b = blockIdx.z, c = blockIdx.y;
    int d = blockIdx.x * 256 + threadIdx.x;
    const float2* p = (const float2*)cv + ((size_t)b * S_ + c * CLEN) * D_ + d;
    float P = 1.0f, V = 0.0f;
    for (int s = 0; s < CLEN; s++) {
        float2 e = *p;
        P *= e.x;
        V = e.x * V + e.y;
        p += D_;
    }
    size_t idx = ((size_t)(b * CHUNKS + c)) * D_ + d;
    Cc[idx] = P; Vc[idx] = V;
}

// phase B: scan chunk states; record each chunk's initial h
__global__ void scanB_k(const float* __restrict__ Cc, const float* __restrict__ Vc,
                        float* __restrict__ Hi) {
    int b = blockIdx.y;
    int d = blockIdx.x * 256 + threadIdx.x;
    float h = 0.0f;
    for (int c = 0; c < CHUNKS; c++) {
        size_t idx = ((size_t)(b * CHUNKS + c)) * D_ + d;
        Hi[idx] = h;
        h = Cc[idx] * h + Vc[idx];
    }
}

// phase C: replay with true initial h; emit bf16 h and f32 new_state
__global__ void scanC_k(const float* __restrict__ cv, const float* __restrict__ Hi,
                        __hip_bfloat16* __restrict__ hout, float* __restrict__ ns) {
    int b = blockIdx.z, c = blockIdx.y;
    int d = blockIdx.x * 256 + threadIdx.x;
    const float2* p = (const float2*)cv + ((size_t)b * S_ + c * CLEN) * D_ + d;
    float h = Hi[((size_t)(b * CHUNKS + c)) * D_ + d];
    for (int s = 0; s < CLEN; s++) {
        float2 e = *p;
        h = e.x * h + e.y;
        hout[((size_t)b * S_ + c * CLEN + s) * D_ + d] = __float2bfloat16(h);
        if (c * CLEN + s == S_ - 1) ns[b * D_ + d] = h;
        p += D_;
    }
}

__global__ void aux_k(float* o) { if (threadIdx.x == 0) o[0] = 0.0f; }

// ---------------- launcher ----------------
extern "C" void kernel_launch(void* const* d_in, const int* in_sizes, int n_in,
                              void* d_out_v, int out_size, void* d_ws, size_t ws_size,
                              hipStream_t stream) {
    const float* inputs = (const float*)d_in[0];
    const float* nw     = (const float*)d_in[1];
    const float* rw     = (const float*)d_in[2];
    const float* rb     = (const float*)d_in[3];
    const float* whg_e  = (const float*)d_in[4];
    const float* wout_e = (const float*)d_in[5];
    float* out = (float*)d_out_v;

    float* ws = (float*)d_ws;
    float*          cv      = ws;                               // 16777216 f32 (float2 pairs)
    __hip_bfloat16* x_bf    = (__hip_bfloat16*)(ws + 16777216); // 8388608 bf16
    __hip_bfloat16* h_bf    = (__hip_bfloat16*)(ws + 20971520); // 8388608 bf16
    __hip_bfloat16* Whg_bf  = (__hip_bfloat16*)(ws + 25165824); // 8388608 bf16
    __hip_bfloat16* Wout_bf = (__hip_bfloat16*)(ws + 29360128); // 4194304 bf16
    float* xsum  = ws + 31457280;  // 4096
    float* probs = ws + 31461376;  // 32
    float* Cc    = ws + 31461408;  // 131072
    float* Vc    = ws + 31592480;  // 131072
    float* Hi    = ws + 31723552;  // 131072

    hipMemsetAsync(xsum, 0, (size_t)B_ * D_ * sizeof(float), stream);

    rmsnorm_k<<<dim3(S_, B_), 256, 0, stream>>>(inputs, nw, x_bf);
    xsum_k<<<dim3(D_ / 256, B_, 16), 256, 0, stream>>>(x_bf, xsum);
    router_k<<<1, 256, 0, stream>>>(xsum, rw, rb, probs);
    mix_k<<<12288, 256, 0, stream>>>(probs, whg_e, wout_e, Whg_bf, Wout_bf);

    // fused GEMM1 + (c,v): grid x = hidden cols / 64, y = rows / 128, z = batch
    gemm_hg_cv<<<dim3(D_ / 64, S_ / 128, B_), 256, 0, stream>>>(x_bf, Whg_bf, cv);

    scanA_k<<<dim3(D_ / 256, CHUNKS, B_), 256, 0, stream>>>(cv, Cc, Vc);
    scanB_k<<<dim3(D_ / 256, B_), 256, 0, stream>>>(Cc, Vc, Hi);
    scanC_k<<<dim3(D_ / 256, CHUNKS, B_), 256, 0, stream>>>(
        cv, Hi, h_bf, out + (size_t)B_ * S_ * D_);

    // out[b] = h[b] (2048x1024) * Wout[b]^T + inputs[b]
    gemm_bf16_bt<<<dim3(D_ / TN, S_ / TM, B_), 256, 0, stream>>>(
        h_bf, Wout_bf, out, inputs, S_, D_, D_,
        (size_t)S_ * D_, (size_t)D_ * D_, (size_t)S_ * D_, (size_t)S_ * D_);

    aux_k<<<1, 64, 0, stream>>>(out + (size_t)B_ * S_ * D_ + (size_t)B_ * D_);
}

// Round 4
// 345.906 us; speedup vs baseline: 3.2742x; 1.0365x over previous
//
#include <hip/hip_runtime.h>
#include <hip/hip_bf16.h>

#define B_  4
#define S_  2048
#define D_  1024
#define E_  8
#define K2_ 2048   // 2*D

#define CHUNKS 64
#define CLEN   32  // CHUNKS*CLEN == S_

typedef __attribute__((ext_vector_type(8))) short short8;   // 8 bf16 (4 VGPRs)
typedef __attribute__((ext_vector_type(4))) float floatx4;  // 4 fp32 acc

__device__ __forceinline__ void gld16(const void* g, const void* l) {
    __builtin_amdgcn_global_load_lds(
        (const __attribute__((address_space(1))) unsigned int*)g,
        (__attribute__((address_space(3))) unsigned int*)l, 16, 0, 0);
}

// ---------------- 1. RMSNorm (f32 in -> bf16 out) ----------------
__global__ void rmsnorm_k(const float* __restrict__ in, const float* __restrict__ nw,
                          __hip_bfloat16* __restrict__ x) {
    int b = blockIdx.y, s = blockIdx.x, t = threadIdx.x;
    const float* row = in + ((size_t)b * S_ + s) * D_;
    float v[4]; float ss = 0.0f;
#pragma unroll
    for (int i = 0; i < 4; i++) { v[i] = row[t + 256 * i]; ss += v[i] * v[i]; }
#pragma unroll
    for (int o = 32; o > 0; o >>= 1) ss += __shfl_down(ss, o, 64);
    __shared__ float ls[4];
    if ((t & 63) == 0) ls[t >> 6] = ss;
    __syncthreads();
    float tot = ls[0] + ls[1] + ls[2] + ls[3];
    float rs = rsqrtf(tot * (1.0f / (float)D_) + 1e-6f);
    __hip_bfloat16* xr = x + ((size_t)b * S_ + s) * D_;
#pragma unroll
    for (int i = 0; i < 4; i++)
        xr[t + 256 * i] = __float2bfloat16(v[i] * rs * nw[t + 256 * i]);
}

// ---------------- 2a. column sums of x over S (router mean) ----------------
__global__ void xsum_k(const __hip_bfloat16* __restrict__ x, float* __restrict__ xs) {
    int d = blockIdx.x * 256 + threadIdx.x;
    int b = blockIdx.y;
    int s0 = blockIdx.z * 128;
    const __hip_bfloat16* p = x + ((size_t)b * S_ + s0) * D_ + d;
    float acc = 0.0f;
#pragma unroll 4
    for (int s = 0; s < 128; s++) { acc += __bfloat162float(*p); p += D_; }
    atomicAdd(&xs[b * D_ + d], acc);
}

// ---------------- 2b. router logits + softmax (+ aux_loss=0) ----------------
__global__ void router_k(const float* __restrict__ xs, const float* __restrict__ rw,
                         const float* __restrict__ rb, float* __restrict__ probs,
                         float* __restrict__ aux) {
    int t = threadIdx.x;
    if (t == 255) *aux = 0.0f;
    int pair = t >> 3, sub = t & 7;
    int b = pair >> 3, e = pair & 7;
    float acc = 0.0f;
    for (int d = sub; d < D_; d += 8) acc += xs[b * D_ + d] * rw[e * D_ + d];
#pragma unroll
    for (int o = 4; o > 0; o >>= 1) acc += __shfl_down(acc, o, 8);
    __shared__ float lg[32];
    if (sub == 0) lg[pair] = acc * (1.0f / (float)S_) + rb[e];
    __syncthreads();
    if (t < 4) {
        float m = -1e30f;
        for (int e2 = 0; e2 < 8; e2++) m = fmaxf(m, lg[t * 8 + e2]);
        float ssum = 0.0f; float ex[8];
        for (int e2 = 0; e2 < 8; e2++) { ex[e2] = expf(lg[t * 8 + e2] - m); ssum += ex[e2]; }
        for (int e2 = 0; e2 < 8; e2++) probs[t * 8 + e2] = ex[e2] / ssum;
    }
}

// ---------------- 3. mix expert weights (f32 experts -> bf16 mixed) ----------------
__global__ void mix_k(const float* __restrict__ probs, const float* __restrict__ whg_e,
                      const float* __restrict__ wout_e, __hip_bfloat16* __restrict__ Whg,
                      __hip_bfloat16* __restrict__ Wout) {
    __shared__ float P[32];
    int t = threadIdx.x;
    if (t < 32) P[t] = probs[t];
    __syncthreads();
    size_t i = (size_t)blockIdx.x * 256 + t;
    const size_t T1 = (size_t)K2_ * D_;
    const size_t T2 = (size_t)D_ * D_;
    if (i < T1) {
        float a0 = 0, a1 = 0, a2 = 0, a3 = 0;
#pragma unroll
        for (int e = 0; e < 8; e++) {
            float w = whg_e[(size_t)e * T1 + i];
            a0 += P[0 * 8 + e] * w; a1 += P[1 * 8 + e] * w;
            a2 += P[2 * 8 + e] * w; a3 += P[3 * 8 + e] * w;
        }
        Whg[0 * T1 + i] = __float2bfloat16(a0); Whg[1 * T1 + i] = __float2bfloat16(a1);
        Whg[2 * T1 + i] = __float2bfloat16(a2); Whg[3 * T1 + i] = __float2bfloat16(a3);
    } else {
        size_t j = i - T1;
        float a0 = 0, a1 = 0, a2 = 0, a3 = 0;
#pragma unroll
        for (int e = 0; e < 8; e++) {
            float w = wout_e[(size_t)e * T2 + j];
            a0 += P[0 * 8 + e] * w; a1 += P[1 * 8 + e] * w;
            a2 += P[2 * 8 + e] * w; a3 += P[3 * 8 + e] * w;
        }
        Wout[0 * T2 + j] = __float2bfloat16(a0); Wout[1 * T2 + j] = __float2bfloat16(a1);
        Wout[2 * T2 + j] = __float2bfloat16(a2); Wout[3 * T2 + j] = __float2bfloat16(a3);
    }
}

// ---------------- 4. fused GEMM1 + (c,v) epilogue ----------------
// XOR-swizzled LDS: position (r, p) holds global 16B-chunk p ^ (r&7).
__global__ __launch_bounds__(256) void gemm_hg_cv(
    const __hip_bfloat16* __restrict__ A, const __hip_bfloat16* __restrict__ Bm,
    float* __restrict__ cv) {
    const int K = D_;
    int bz = blockIdx.z;
    A  += (size_t)bz * S_ * D_;
    Bm += (size_t)bz * K2_ * D_;
    float2* CV = (float2*)cv + (size_t)bz * S_ * D_;
    int m0 = blockIdx.y * 128, n0 = blockIdx.x * 64;
    __shared__ __hip_bfloat16 lA[128][64];
    __shared__ __hip_bfloat16 lBh[64][64];
    __shared__ __hip_bfloat16 lBg[64][64];
    int t = threadIdx.x;
    int w = t >> 6, lane = t & 63;
    int lm = lane & 15, quad = lane >> 4;
    int wr = w >> 1, wc = w & 1;             // wave tile: 64 rows x 32 cols (x2 h/g)
    floatx4 acch[4][2] = {};
    floatx4 accg[4][2] = {};
    int srow = lane >> 3;                    // 0..7
    int swzb = ((lane & 7) ^ srow) * 16;     // swizzled source byte-chunk
    const __hip_bfloat16* Bh = Bm;                    // hidden rows 0..1023
    const __hip_bfloat16* Bg = Bm + (size_t)D_ * K;   // gate rows 1024..2047

    for (int k0 = 0; k0 < K; k0 += 64) {
#pragma unroll
        for (int it = 0; it < 4; it++) {
            int r0 = (w * 4 + it) * 8;
            gld16((const char*)(A + (size_t)(m0 + r0 + srow) * K + k0) + swzb,
                  &lA[r0][0]);
        }
#pragma unroll
        for (int it = 0; it < 2; it++) {
            int r0 = (w * 2 + it) * 8;
            gld16((const char*)(Bh + (size_t)(n0 + r0 + srow) * K + k0) + swzb,
                  &lBh[r0][0]);
            gld16((const char*)(Bg + (size_t)(n0 + r0 + srow) * K + k0) + swzb,
                  &lBg[r0][0]);
        }
        __syncthreads();
#pragma unroll
        for (int kk = 0; kk < 64; kk += 32) {
            short8 af[4], bh[2], bg[2];
#pragma unroll
            for (int i = 0; i < 4; i++) {
                int p = (((kk >> 3) + quad) ^ (lm & 7)) * 8;
                af[i] = *(const short8*)(&lA[wr * 64 + i * 16 + lm][p]);
            }
#pragma unroll
            for (int j = 0; j < 2; j++) {
                int p = (((kk >> 3) + quad) ^ (lm & 7)) * 8;
                bh[j] = *(const short8*)(&lBh[wc * 32 + j * 16 + lm][p]);
                bg[j] = *(const short8*)(&lBg[wc * 32 + j * 16 + lm][p]);
            }
#pragma unroll
            for (int i = 0; i < 4; i++)
#pragma unroll
                for (int j = 0; j < 2; j++) {
                    acch[i][j] = __builtin_amdgcn_mfma_f32_16x16x32_bf16(
                        af[i], bh[j], acch[i][j], 0, 0, 0);
                    accg[i][j] = __builtin_amdgcn_mfma_f32_16x16x32_bf16(
                        af[i], bg[j], accg[i][j], 0, 0, 0);
                }
        }
        __syncthreads();
    }
#pragma unroll
    for (int i = 0; i < 4; i++) {
#pragma unroll
        for (int j = 0; j < 2; j++) {
#pragma unroll
            for (int r = 0; r < 4; r++) {
                int m = m0 + wr * 64 + i * 16 + quad * 4 + r;
                int n = n0 + wc * 32 + j * 16 + lm;
                float hid = acch[i][j][r];
                float g   = accg[i][j][r];
                float c  = 1.0f / (1.0f + expf(g));    // sigmoid(-g)
                float sg = 1.0f / (1.0f + expf(-g));   // sigmoid(g)
                float gfn = (hid >= 0.0f) ? (hid + 0.5f)
                                          : (1.0f / (1.0f + expf(-hid)));
                CV[(size_t)m * D_ + n] = make_float2(c, sg * gfn);
            }
        }
    }
}

// ---------------- 6. bf16 MFMA GEMM, C = A * B^T (+R), XOR-swizzled LDS ----
#define TM 128
#define TN 128
#define TBK 64
__global__ __launch_bounds__(256) void gemm_bf16_bt(
    const __hip_bfloat16* __restrict__ A, const __hip_bfloat16* __restrict__ Bm,
    float* __restrict__ C, const float* __restrict__ R,
    int M, int N, int K, size_t sa, size_t sb, size_t sc, size_t sr) {
    int bz = blockIdx.z;
    A += (size_t)bz * sa; Bm += (size_t)bz * sb; C += (size_t)bz * sc;
    if (R) R += (size_t)bz * sr;
    int m0 = blockIdx.y * TM, n0 = blockIdx.x * TN;
    __shared__ __hip_bfloat16 lA[TM][TBK];
    __shared__ __hip_bfloat16 lB[TN][TBK];
    int t = threadIdx.x;
    int w = t >> 6, lane = t & 63;
    int lm = lane & 15, quad = lane >> 4;
    int wr = w >> 1, wc = w & 1;
    floatx4 acc[4][4] = {};
    int srow = lane >> 3;
    int swzb = ((lane & 7) ^ srow) * 16;

    for (int k0 = 0; k0 < K; k0 += TBK) {
#pragma unroll
        for (int it = 0; it < 4; it++) {
            int r0 = (w * 4 + it) * 8;
            gld16((const char*)(A + (size_t)(m0 + r0 + srow) * K + k0) + swzb,
                  &lA[r0][0]);
            gld16((const char*)(Bm + (size_t)(n0 + r0 + srow) * K + k0) + swzb,
                  &lB[r0][0]);
        }
        __syncthreads();
#pragma unroll
        for (int kk = 0; kk < TBK; kk += 32) {
            short8 af[4], bf[4];
#pragma unroll
            for (int i = 0; i < 4; i++) {
                int p = (((kk >> 3) + quad) ^ (lm & 7)) * 8;
                af[i] = *(const short8*)(&lA[wr * 64 + i * 16 + lm][p]);
            }
#pragma unroll
            for (int j = 0; j < 4; j++) {
                int p = (((kk >> 3) + quad) ^ (lm & 7)) * 8;
                bf[j] = *(const short8*)(&lB[wc * 64 + j * 16 + lm][p]);
            }
#pragma unroll
            for (int i = 0; i < 4; i++)
#pragma unroll
                for (int j = 0; j < 4; j++)
                    acc[i][j] = __builtin_amdgcn_mfma_f32_16x16x32_bf16(
                        af[i], bf[j], acc[i][j], 0, 0, 0);
        }
        __syncthreads();
    }
#pragma unroll
    for (int i = 0; i < 4; i++) {
#pragma unroll
        for (int j = 0; j < 4; j++) {
#pragma unroll
            for (int r = 0; r < 4; r++) {
                int m = m0 + wr * 64 + i * 16 + quad * 4 + r;
                int n = n0 + wc * 64 + j * 16 + lm;
                float v = acc[i][j][r];
                if (R) v += R[(size_t)m * N + n];
                C[(size_t)m * N + n] = v;
            }
        }
    }
}

// ---------------- 5. chunked LINEAR scan over cv (d-pairs via float4) -------
// phase A: per-chunk composition
__global__ void scanA_k(const float* __restrict__ cv, float* __restrict__ Cc,
                        float* __restrict__ Vc) {
    int b = blockIdx.z, c = blockIdx.y;
    int d2 = blockIdx.x * 256 + threadIdx.x;   // d-pair index 0..511
    const float4* p = (const float4*)cv + (size_t)(b * S_ + c * CLEN) * (D_ / 2) + d2;
    float P0 = 1.0f, V0 = 0.0f, P1 = 1.0f, V1 = 0.0f;
#pragma unroll 4
    for (int s = 0; s < CLEN; s++) {
        float4 e = p[(size_t)s * (D_ / 2)];
        P0 *= e.x; V0 = e.x * V0 + e.y;
        P1 *= e.z; V1 = e.z * V1 + e.w;
    }
    size_t idx = ((size_t)(b * CHUNKS + c)) * D_ + 2 * d2;
    Cc[idx] = P0; Vc[idx] = V0; Cc[idx + 1] = P1; Vc[idx + 1] = V1;
}

// phase B: scan chunk states; record each chunk's initial h
__global__ void scanB_k(const float* __restrict__ Cc, const float* __restrict__ Vc,
                        float* __restrict__ Hi) {
    int b = blockIdx.y;
    int d = blockIdx.x * 256 + threadIdx.x;
    float h = 0.0f;
    for (int c = 0; c < CHUNKS; c++) {
        size_t idx = ((size_t)(b * CHUNKS + c)) * D_ + d;
        Hi[idx] = h;
        h = Cc[idx] * h + Vc[idx];
    }
}

// phase C: replay with true initial h; emit bf16 h and f32 new_state
__global__ void scanC_k(const float* __restrict__ cv, const float* __restrict__ Hi,
                        __hip_bfloat162* __restrict__ hout, float* __restrict__ ns) {
    int b = blockIdx.z, c = blockIdx.y;
    int d2 = blockIdx.x * 256 + threadIdx.x;
    const float4* p = (const float4*)cv + (size_t)(b * S_ + c * CLEN) * (D_ / 2) + d2;
    size_t hidx = ((size_t)(b * CHUNKS + c)) * D_ + 2 * d2;
    float h0 = Hi[hidx], h1 = Hi[hidx + 1];
#pragma unroll 4
    for (int s = 0; s < CLEN; s++) {
        float4 e = p[(size_t)s * (D_ / 2)];
        h0 = e.x * h0 + e.y;
        h1 = e.z * h1 + e.w;
        __hip_bfloat162 hh;
        hh.x = __float2bfloat16(h0); hh.y = __float2bfloat16(h1);
        hout[(size_t)(b * S_ + c * CLEN + s) * (D_ / 2) + d2] = hh;
    }
    if (c == CHUNKS - 1) { ns[b * D_ + 2 * d2] = h0; ns[b * D_ + 2 * d2 + 1] = h1; }
}

// ---------------- launcher ----------------
extern "C" void kernel_launch(void* const* d_in, const int* in_sizes, int n_in,
                              void* d_out_v, int out_size, void* d_ws, size_t ws_size,
                              hipStream_t stream) {
    const float* inputs = (const float*)d_in[0];
    const float* nw     = (const float*)d_in[1];
    const float* rw     = (const float*)d_in[2];
    const float* rb     = (const float*)d_in[3];
    const float* whg_e  = (const float*)d_in[4];
    const float* wout_e = (const float*)d_in[5];
    float* out = (float*)d_out_v;

    float* ws = (float*)d_ws;
    float*          cv      = ws;                               // 16777216 f32 (float2 pairs)
    __hip_bfloat16* x_bf    = (__hip_bfloat16*)(ws + 16777216); // 8388608 bf16
    __hip_bfloat16* h_bf    = (__hip_bfloat16*)(ws + 20971520); // 8388608 bf16
    __hip_bfloat16* Whg_bf  = (__hip_bfloat16*)(ws + 25165824); // 8388608 bf16
    __hip_bfloat16* Wout_bf = (__hip_bfloat16*)(ws + 29360128); // 4194304 bf16
    float* xsum  = ws + 31457280;  // 4096
    float* probs = ws + 31461376;  // 32
    float* Cc    = ws + 31461408;  // 262144
    float* Vc    = ws + 31723552;  // 262144
    float* Hi    = ws + 31985696;  // 262144

    hipMemsetAsync(xsum, 0, (size_t)B_ * D_ * sizeof(float), stream);

    rmsnorm_k<<<dim3(S_, B_), 256, 0, stream>>>(inputs, nw, x_bf);
    xsum_k<<<dim3(D_ / 256, B_, 16), 256, 0, stream>>>(x_bf, xsum);
    router_k<<<1, 256, 0, stream>>>(xsum, rw, rb, probs,
                                    out + (size_t)B_ * S_ * D_ + (size_t)B_ * D_);
    mix_k<<<12288, 256, 0, stream>>>(probs, whg_e, wout_e, Whg_bf, Wout_bf);

    // fused GEMM1 + (c,v)
    gemm_hg_cv<<<dim3(D_ / 64, S_ / 128, B_), 256, 0, stream>>>(x_bf, Whg_bf, cv);

    scanA_k<<<dim3(D_ / 512, CHUNKS, B_), 256, 0, stream>>>(cv, Cc, Vc);
    scanB_k<<<dim3(D_ / 256, B_), 256, 0, stream>>>(Cc, Vc, Hi);
    scanC_k<<<dim3(D_ / 512, CHUNKS, B_), 256, 0, stream>>>(
        cv, Hi, (__hip_bfloat162*)h_bf, out + (size_t)B_ * S_ * D_);

    // out[b] = h[b] (2048x1024) * Wout[b]^T + inputs[b]
    gemm_bf16_bt<<<dim3(D_ / TN, S_ / TM, B_), 256, 0, stream>>>(
        h_bf, Wout_bf, out, inputs, S_, D_, D_,
        (size_t)S_ * D_, (size_t)D_ * D_, (size_t)S_ * D_, (size_t)S_ * D_);
}